// Round 8
// baseline (215.717 us; speedup 1.0000x reference)
//
#include <hip/hip_runtime.h>
#include <hip/hip_bf16.h>
#include <math.h>

#define NH   16
#define NKV  4
#define HD   64
#define B_   2
#define T_   2048
#define C_   1024
#define QKVN 1536   // fused q(1024) | k(256) | v(256)

typedef __attribute__((ext_vector_type(8))) short short8;
typedef __attribute__((ext_vector_type(4))) float v4f;

__device__ inline ushort f2bf(float f) {
    union { float f; uint32_t u; } v; v.f = f;
    uint32_t r = v.u + 0x7fffu + ((v.u >> 16) & 1u);
    return (ushort)(r >> 16);
}

// pack two f32 -> one dword of bf16 (HW op on gfx950 if available)
__device__ inline uint pk_bf16(float a, float b) {
#if __has_builtin(__builtin_amdgcn_cvt_pk_bf16_f32)
    auto v = __builtin_amdgcn_cvt_pk_bf16_f32(a, b);
    union { decltype(v) v2; uint u; } cv; cv.v2 = v; return cv.u;
#else
    return (uint)f2bf(a) | ((uint)f2bf(b) << 16);
#endif
}

__device__ inline float ex2(float x) {
#if __has_builtin(__builtin_amdgcn_exp2f)
    return __builtin_amdgcn_exp2f(x);
#else
    return exp2f(x);
#endif
}

// async global->LDS, 16B per lane; LDS dest wave-uniform base + lane*16
__device__ inline void async16(const void* g, void* l) {
    __builtin_amdgcn_global_load_lds(
        (const __attribute__((address_space(1))) unsigned int*)g,
        (__attribute__((address_space(3))) unsigned int*)l, 16, 0, 0);
}

// ---------------- prep: x f32->bf16 convert + 4 weight transposes ----------
__global__ __launch_bounds__(256) void prep(
    const float* __restrict__ x,
    const float* __restrict__ Wq, const float* __restrict__ Wk,
    const float* __restrict__ Wv, const float* __restrict__ Wo,
    ushort* __restrict__ xb, ushort* __restrict__ WqkvT, ushort* __restrict__ WoT)
{
    const int bx = blockIdx.x;
    const int tid = threadIdx.x;
    if (bx < 640) {
        __shared__ float tile[64][65];
        const int cb = bx >> 4;
        const int kb = bx & 15;
        const float* src; ushort* dst; int N, nb;
        if (cb < 16)      { src = Wq; dst = WqkvT;                     N = 1024; nb = cb; }
        else if (cb < 20) { src = Wk; dst = WqkvT + (size_t)1024 * C_; N = 256;  nb = cb - 16; }
        else if (cb < 24) { src = Wv; dst = WqkvT + (size_t)1280 * C_; N = 256;  nb = cb - 20; }
        else              { src = Wo; dst = WoT;                       N = 1024; nb = cb - 24; }
        const int k0 = kb * 64, n0 = nb * 64;
        #pragma unroll
        for (int it = 0; it < 4; ++it) {
            int r = (tid >> 4) + it * 16;
            int c = (tid & 15) * 4;
            float4 v = *(const float4*)(src + (size_t)(k0 + r) * N + n0 + c);
            tile[r][c] = v.x; tile[r][c + 1] = v.y; tile[r][c + 2] = v.z; tile[r][c + 3] = v.w;
        }
        __syncthreads();
        #pragma unroll
        for (int it = 0; it < 4; ++it) {
            int r = (tid >> 4) + it * 16;
            int c = (tid & 15) * 4;
            ushort4 o;
            o.x = f2bf(tile[c + 0][r]); o.y = f2bf(tile[c + 1][r]);
            o.z = f2bf(tile[c + 2][r]); o.w = f2bf(tile[c + 3][r]);
            *(ushort4*)(dst + (size_t)(n0 + r) * C_ + k0 + c) = o;
        }
    } else {
        int i = ((bx - 640) * 256 + tid) * 4;   // covers 4096*1024 exactly
        float4 v = *(const float4*)(x + i);
        ushort4 o; o.x = f2bf(v.x); o.y = f2bf(v.y); o.z = f2bf(v.z); o.w = f2bf(v.w);
        *(ushort4*)(xb + i) = o;
    }
}

// ---------------- bf16 MFMA GEMM: C[M,N] = A[M,K] @ Bt[N,K]^T --------------
// m97 geometry: 128x128 tile, BK=32, 4 waves (2x2), 16 MFMA/wave/iter.
// ROPE path (QKV gemm, per-wave 64-col span = one head):
//   col0<1024   -> rope, scale by 0.125*log2e (exp2-domain softmax)
//   1024..1280  -> rope only (k)
//   col0>=1280  -> v: store DIRECTLY transposed into vT
template <bool BF16OUT, bool ROPE>
__global__ __launch_bounds__(256) void gemm_bf16bt(
    const ushort* __restrict__ A, const ushort* __restrict__ Bt,
    void* __restrict__ Cout, ushort* __restrict__ vTout,
    const float* __restrict__ cs, const float* __restrict__ sn,
    int M, int N, int K)
{
    __shared__ __align__(16) short As[128 * 32];
    __shared__ __align__(16) short Bs[128 * 32];

    const int tid  = threadIdx.x;
    const int lane = tid & 63;
    const int wid  = tid >> 6;
    const int l16  = lane & 15;
    const int quad = lane >> 4;
    const int wm   = wid >> 1, wn = wid & 1;
    const int m0   = blockIdx.y * 128;
    const int n0   = blockIdx.x * 128;

    v4f acc[4][4];
    #pragma unroll
    for (int i = 0; i < 4; ++i)
        #pragma unroll
        for (int j = 0; j < 4; ++j) acc[i][j] = (v4f){0.f, 0.f, 0.f, 0.f};

    for (int k0 = 0; k0 < K; k0 += 32) {
        __syncthreads();
        {
            const ushort* ag = A  + (size_t)(m0 + wid * 32 + (lane >> 2)) * K + k0 + (lane & 3) * 8;
            async16(ag,                  &As[(wid * 32) * 32]);
            async16(ag + (size_t)16 * K, &As[(wid * 32 + 16) * 32]);
            const ushort* bg = Bt + (size_t)(n0 + wid * 32 + (lane >> 2)) * K + k0 + (lane & 3) * 8;
            async16(bg,                  &Bs[(wid * 32) * 32]);
            async16(bg + (size_t)16 * K, &Bs[(wid * 32 + 16) * 32]);
        }
        __syncthreads();

        short8 af[4], bf[4];
        #pragma unroll
        for (int t = 0; t < 4; ++t) {
            af[t] = *(const short8*)&As[(wm * 64 + t * 16 + l16) * 32 + quad * 8];
            bf[t] = *(const short8*)&Bs[(wn * 64 + t * 16 + l16) * 32 + quad * 8];
        }
        #pragma unroll
        for (int i = 0; i < 4; ++i)
            #pragma unroll
            for (int j = 0; j < 4; ++j)
                acc[i][j] = __builtin_amdgcn_mfma_f32_16x16x32_bf16(af[i], bf[j], acc[i][j], 0, 0, 0);
    }

    const int col0 = n0 + wn * 64;

    if (ROPE && col0 >= 1280) {
        // v tile: store transposed to vT[(b*256 + (col-1280))][t]
        #pragma unroll
        for (int i = 0; i < 4; ++i) {
            const int row = m0 + wm * 64 + i * 16 + quad * 4;   // 4 consecutive t
            const int bb  = row >> 11;
            const int t   = row & (T_ - 1);
            #pragma unroll
            for (int j = 0; j < 4; ++j) {
                const int vc = col0 - 1280 + j * 16 + l16;
                ushort4 o;
                o.x = f2bf(acc[i][j][0]); o.y = f2bf(acc[i][j][1]);
                o.z = f2bf(acc[i][j][2]); o.w = f2bf(acc[i][j][3]);
                *(ushort4*)(vTout + (size_t)(bb * 256 + vc) * T_ + t) = o;
            }
        }
        return;
    }

    if (ROPE) {
        // q gets 0.125 * log2(e) so attention works in exp2 domain
        const float qs = (col0 < 1024) ? 0.18033688f : 1.0f;
        #pragma unroll
        for (int i = 0; i < 4; ++i) {
            #pragma unroll
            for (int r = 0; r < 4; ++r) {
                const int row = m0 + wm * 64 + i * 16 + quad * 4 + r;
                const int t = row & (T_ - 1);
                #pragma unroll
                for (int j = 0; j < 2; ++j) {
                    const int d = j * 16 + l16;
                    float cv = cs[t * 32 + d] * qs, sv = sn[t * 32 + d] * qs;
                    float x1 = acc[i][j][r], x2 = acc[i][j + 2][r];
                    acc[i][j][r]     = x1 * cv - x2 * sv;
                    acc[i][j + 2][r] = x2 * cv + x1 * sv;
                }
            }
        }
    }

    #pragma unroll
    for (int i = 0; i < 4; ++i) {
        #pragma unroll
        for (int r = 0; r < 4; ++r) {
            const int row = m0 + wm * 64 + i * 16 + quad * 4 + r;
            #pragma unroll
            for (int j = 0; j < 4; ++j) {
                const int col = n0 + wn * 64 + j * 16 + l16;
                if (BF16OUT)
                    ((ushort*)Cout)[(size_t)row * N + col] = f2bf(acc[i][j][r]);
                else
                    ((float*)Cout)[(size_t)row * N + col] = acc[i][j][r];
            }
        }
    }
}

// ---------------- MFMA flash attention: 128-key chunks, exp2 softmax ------
// Grid 512, XCD swizzle (blockIdx&7 -> (b,kvh), K/V slice L2-resident),
// paired q-tiles (31-p then p). 128-key chunks: 17 barriers/block (was 33),
// one softmax tree + one P roundtrip + one O-rescale per 128 keys.
#define PSTR 136
__global__ __launch_bounds__(256, 2) void attn_mfma(
    const ushort* __restrict__ qkv, const ushort* __restrict__ vT,
    ushort* __restrict__ y)
{
    __shared__ __align__(16) short Ks[2][128 * 64];
    __shared__ __align__(16) short Ps[4][16][PSTR];

    const int tid  = threadIdx.x;
    const int wid  = tid >> 6;
    const int ln   = tid & 63;
    const int l16  = ln & 15;
    const int quad = ln >> 4;

    const int bi   = blockIdx.x;          // 0..511
    const int xcd  = bi & 7;
    const int b    = xcd >> 2;
    const int kvh  = xcd & 3;
    const int jj   = bi >> 3;             // 0..63
    const int h    = kvh * 4 + (jj & 3);
    const int pr   = jj >> 2;             // 0..15

    const ushort* kbase = qkv + (size_t)(b * T_) * QKVN + 1024 + kvh * HD;
    const ushort* vtb   = vT + (size_t)(b * 256 + kvh * HD) * T_;

    const int r0   = wid * 32;                    // staging rows of this wave
    const int srow = ln >> 3;
    const int sblk = ((ln & 7) ^ srow) * 8;       // XOR-swizzled source col
    const int sl0  = (quad ^ (l16 & 7)) * 8;      // frag slot, d-blocks 0..3
    const int sl1  = sl0 ^ 32;                    // d-blocks 4..7

    #pragma unroll 1
    for (int pass = 0; pass < 2; ++pass) {
        const int tb = pass ? pr : (31 - pr);     // heavy tile first
        const int q0 = tb * 64;
        const int nch = tb / 2 + 1;               // 128-key chunks

        // Q B-fragments (pre-scaled by 0.125*log2e): B[n=l16][k=quad*8+j]
        short8 qf0, qf1;
        {
            const ushort* qrow = qkv + (size_t)(b * T_ + q0 + wid * 16 + l16) * QKVN + h * HD;
            qf0 = *(const short8*)(qrow + quad * 8);
            qf1 = *(const short8*)(qrow + 32 + quad * 8);
        }

        v4f oacc[4];
        #pragma unroll
        for (int t = 0; t < 4; ++t) oacc[t] = (v4f){0.f, 0.f, 0.f, 0.f};
        float m = -1e30f, l = 0.f;

        if (pass) __syncthreads();   // protect Ks reuse across passes

        // prologue: stage K chunk 0 (128 rows) into buf 0
        {
            const ushort* kg = kbase + (size_t)(r0 + srow) * QKVN + sblk;
            async16(kg,                     &Ks[0][(r0     ) * 64]);
            async16(kg + (size_t) 8 * QKVN, &Ks[0][(r0 +  8) * 64]);
            async16(kg + (size_t)16 * QKVN, &Ks[0][(r0 + 16) * 64]);
            async16(kg + (size_t)24 * QKVN, &Ks[0][(r0 + 24) * 64]);
        }

        for (int c = 0; c < nch; ++c) {
            const int key0 = c * 128;
            __syncthreads();   // vmcnt(0): drains chunk-c K DMA

            // V A-frags for chunk c, direct from global (L2-hit; issued early)
            short8 vf[4][4];
            #pragma unroll
            for (int t = 0; t < 4; ++t) {
                const ushort* vrow = vtb + (size_t)(t * 16 + l16) * T_ + key0;
                #pragma unroll
                for (int seg = 0; seg < 4; ++seg)
                    vf[t][seg] = *(const short8*)(vrow + seg * 32 + quad * 8);
            }

            // prefetch K chunk c+1
            if (c + 1 < nch) {
                const int nb = (c + 1) & 1;
                const ushort* kg = kbase + (size_t)(key0 + 128 + r0 + srow) * QKVN + sblk;
                async16(kg,                     &Ks[nb][(r0     ) * 64]);
                async16(kg + (size_t) 8 * QKVN, &Ks[nb][(r0 +  8) * 64]);
                async16(kg + (size_t)16 * QKVN, &Ks[nb][(r0 + 16) * 64]);
                async16(kg + (size_t)24 * QKVN, &Ks[nb][(r0 + 24) * 64]);
            }
            const short* Kb = Ks[c & 1];

            // ---- S^T = K @ Q^T (row=key, col=query), 8 key-tiles ----
            v4f st[8];
            #pragma unroll
            for (int t = 0; t < 8; ++t) {
                short8 k0f = *(const short8*)&Kb[(t * 16 + l16) * 64 + sl0];
                short8 k1f = *(const short8*)&Kb[(t * 16 + l16) * 64 + sl1];
                v4f s = (v4f){0.f, 0.f, 0.f, 0.f};
                s = __builtin_amdgcn_mfma_f32_16x16x32_bf16(k0f, qf0, s, 0, 0, 0);
                s = __builtin_amdgcn_mfma_f32_16x16x32_bf16(k1f, qf1, s, 0, 0, 0);
                st[t] = s;
            }

            // causal mask: only the chunk containing the diagonal
            if (c == nch - 1) {
                const int qg = wid * 16 + l16 + q0;
                #pragma unroll
                for (int t = 0; t < 8; ++t)
                    #pragma unroll
                    for (int r = 0; r < 4; ++r)
                        if (key0 + t * 16 + quad * 4 + r > qg) st[t][r] = -1e30f;
            }

            // ---- online softmax (exp2 domain), per-lane query scalar ----
            float mx = st[0][0];
            #pragma unroll
            for (int t = 0; t < 8; ++t)
                #pragma unroll
                for (int r = 0; r < 4; ++r) mx = fmaxf(mx, st[t][r]);
            mx = fmaxf(mx, __shfl_xor(mx, 16, 64));
            mx = fmaxf(mx, __shfl_xor(mx, 32, 64));
            float mnew  = fmaxf(m, mx);
            float alpha = ex2(m - mnew);
            m = mnew;
            float p[8][4], sum = 0.f;
            #pragma unroll
            for (int t = 0; t < 8; ++t)
                #pragma unroll
                for (int r = 0; r < 4; ++r) {
                    p[t][r] = ex2(st[t][r] - mnew);
                    sum += p[t][r];
                }
            sum += __shfl_xor(sum, 16, 64);
            sum += __shfl_xor(sum, 32, 64);
            l = l * alpha + sum;

            // write P^T rows: Ps[query=l16][key], packed pairs -> b64
            #pragma unroll
            for (int t = 0; t < 8; ++t) {
                uint2 w;
                w.x = pk_bf16(p[t][0], p[t][1]);
                w.y = pk_bf16(p[t][2], p[t][3]);
                *(uint2*)&Ps[wid][l16][t * 16 + quad * 4] = w;
            }
            #pragma unroll
            for (int t = 0; t < 4; ++t)
                #pragma unroll
                for (int r = 0; r < 4; ++r) oacc[t][r] *= alpha;

            // wave-private P region: drain only this wave's ds ops
            asm volatile("s_waitcnt lgkmcnt(0)" ::: "memory");
            short8 pa[4];
            #pragma unroll
            for (int seg = 0; seg < 4; ++seg)
                pa[seg] = *(const short8*)&Ps[wid][l16][seg * 32 + quad * 8];

            // ---- O^T += V^T @ P^T (4 d-tiles x 4 key-segments) ----
            #pragma unroll
            for (int t = 0; t < 4; ++t)
                #pragma unroll
                for (int seg = 0; seg < 4; ++seg)
                    oacc[t] = __builtin_amdgcn_mfma_f32_16x16x32_bf16(vf[t][seg], pa[seg], oacc[t], 0, 0, 0);
        }

        // epilogue: y[query][h*64+d] = O^T / l
        const float inv = 1.0f / l;
        ushort* yrow = y + (size_t)(b * T_ + q0 + wid * 16 + l16) * (NH * HD) + h * HD;
        #pragma unroll
        for (int t = 0; t < 4; ++t) {
            ushort4 o;
            o.x = f2bf(oacc[t][0] * inv); o.y = f2bf(oacc[t][1] * inv);
            o.z = f2bf(oacc[t][2] * inv); o.w = f2bf(oacc[t][3] * inv);
            *(ushort4*)(yrow + t * 16 + quad * 4) = o;
        }
    }
}

// ---------------- launcher ----------------
extern "C" void kernel_launch(void* const* d_in, const int* in_sizes, int n_in,
                              void* d_out, int out_size, void* d_ws, size_t ws_size,
                              hipStream_t stream)
{
    const float* x    = (const float*)d_in[0];
    const float* cosT = (const float*)d_in[1];
    const float* sinT = (const float*)d_in[2];
    const float* Wq   = (const float*)d_in[3];
    const float* Wk   = (const float*)d_in[4];
    const float* Wv   = (const float*)d_in[5];
    const float* Wo   = (const float*)d_in[6];
    float* out = (float*)d_out;

    const int M = B_ * T_;  // 4096
    ushort* xb     = (ushort*)d_ws;                       // 4096*1024
    ushort* qkv    = xb  + (size_t)M * C_;                // 4096*1536
    ushort* yb     = qkv + (size_t)M * QKVN;              // 4096*1024
    ushort* WqkvT  = yb  + (size_t)M * C_;                // 1536*1024
    ushort* WoT    = WqkvT + (size_t)QKVN * C_;           // 1024*1024
    ushort* vTbuf  = WoT + (size_t)C_ * C_;               // 2*256*2048

    dim3 blk(256);
    // converts + weight transposes, one launch
    prep<<<640 + (M * C_) / 1024, blk, 0, stream>>>(x, Wq, Wk, Wv, Wo, xb, WqkvT, WoT);
    // fused QKV projection: rope(+exp2 scale) epilogue, v written straight to vT
    gemm_bf16bt<true, true><<<dim3(QKVN / 128, M / 128), blk, 0, stream>>>(
        xb, WqkvT, qkv, vTbuf, cosT, sinT, M, QKVN, C_);
    // attention (XCD-swizzled, paired tiles, 128-key chunks)
    attn_mfma<<<512, blk, 0, stream>>>(qkv, vTbuf, yb);
    // output projection (fp32 out)
    gemm_bf16bt<false, false><<<dim3(C_ / 128, M / 128), blk, 0, stream>>>(
        yb, WoT, out, nullptr, nullptr, nullptr, M, C_, C_);
}

// Round 11
// 171.256 us; speedup vs baseline: 1.2596x; 1.2596x over previous
//
#include <hip/hip_runtime.h>
#include <hip/hip_bf16.h>
#include <math.h>

#define NH   16
#define NKV  4
#define HD   64
#define B_   2
#define T_   2048
#define C_   1024
#define QKVN 1536   // fused q(1024) | k(256) | v(256)

typedef __attribute__((ext_vector_type(8))) short short8;
typedef __attribute__((ext_vector_type(4))) float v4f;

__device__ inline ushort f2bf(float f) {
    union { float f; uint32_t u; } v; v.f = f;
    uint32_t r = v.u + 0x7fffu + ((v.u >> 16) & 1u);
    return (ushort)(r >> 16);
}

// pack two f32 -> one dword of bf16
__device__ inline uint pk_bf16(float a, float b) {
#if __has_builtin(__builtin_amdgcn_cvt_pk_bf16_f32)
    auto v = __builtin_amdgcn_cvt_pk_bf16_f32(a, b);
    union { decltype(v) v2; uint u; } cv; cv.v2 = v; return cv.u;
#else
    return (uint)f2bf(a) | ((uint)f2bf(b) << 16);
#endif
}

__device__ inline float ex2(float x) {
#if __has_builtin(__builtin_amdgcn_exp2f)
    return __builtin_amdgcn_exp2f(x);
#else
    return exp2f(x);
#endif
}

// async global->LDS, 16B per lane; LDS dest wave-uniform base + lane*16
__device__ inline void async16(const void* g, void* l) {
    __builtin_amdgcn_global_load_lds(
        (const __attribute__((address_space(1))) unsigned int*)g,
        (__attribute__((address_space(3))) unsigned int*)l, 16, 0, 0);
}

// ---------------- prep: x f32->bf16 convert + 4 weight transposes ----------
__global__ __launch_bounds__(256) void prep(
    const float* __restrict__ x,
    const float* __restrict__ Wq, const float* __restrict__ Wk,
    const float* __restrict__ Wv, const float* __restrict__ Wo,
    ushort* __restrict__ xb, ushort* __restrict__ WqkvT, ushort* __restrict__ WoT)
{
    const int bx = blockIdx.x;
    const int tid = threadIdx.x;
    if (bx < 640) {
        __shared__ float tile[64][65];
        const int cb = bx >> 4;
        const int kb = bx & 15;
        const float* src; ushort* dst; int N, nb;
        if (cb < 16)      { src = Wq; dst = WqkvT;                     N = 1024; nb = cb; }
        else if (cb < 20) { src = Wk; dst = WqkvT + (size_t)1024 * C_; N = 256;  nb = cb - 16; }
        else if (cb < 24) { src = Wv; dst = WqkvT + (size_t)1280 * C_; N = 256;  nb = cb - 20; }
        else              { src = Wo; dst = WoT;                       N = 1024; nb = cb - 24; }
        const int k0 = kb * 64, n0 = nb * 64;
        #pragma unroll
        for (int it = 0; it < 4; ++it) {
            int r = (tid >> 4) + it * 16;
            int c = (tid & 15) * 4;
            float4 v = *(const float4*)(src + (size_t)(k0 + r) * N + n0 + c);
            tile[r][c] = v.x; tile[r][c + 1] = v.y; tile[r][c + 2] = v.z; tile[r][c + 3] = v.w;
        }
        __syncthreads();
        #pragma unroll
        for (int it = 0; it < 4; ++it) {
            int r = (tid >> 4) + it * 16;
            int c = (tid & 15) * 4;
            ushort4 o;
            o.x = f2bf(tile[c + 0][r]); o.y = f2bf(tile[c + 1][r]);
            o.z = f2bf(tile[c + 2][r]); o.w = f2bf(tile[c + 3][r]);
            *(ushort4*)(dst + (size_t)(n0 + r) * C_ + k0 + c) = o;
        }
    } else {
        int i = ((bx - 640) * 256 + tid) * 4;   // covers 4096*1024 exactly
        float4 v = *(const float4*)(x + i);
        ushort4 o; o.x = f2bf(v.x); o.y = f2bf(v.y); o.z = f2bf(v.z); o.w = f2bf(v.w);
        *(ushort4*)(xb + i) = o;
    }
}

// ---------------- bf16 MFMA GEMM: C[M,N] = A[M,K] @ Bt[N,K]^T --------------
// 128(M)x64(N) tile, BK=32, 4 waves stacked along M (wave: 32m x 64n).
// ROPE path (QKV gemm): n0<1024 -> rope + 0.125*log2e scale (exp2 softmax);
// 1024..1280 -> rope only (k); n0>=1280 -> v stored transposed into vT.
template <bool BF16OUT, bool ROPE>
__global__ __launch_bounds__(256) void gemm_bf16bt(
    const ushort* __restrict__ A, const ushort* __restrict__ Bt,
    void* __restrict__ Cout, ushort* __restrict__ vTout,
    const float* __restrict__ cs, const float* __restrict__ sn,
    int M, int N, int K)
{
    __shared__ __align__(16) short As[128 * 32];
    __shared__ __align__(16) short Bs[64 * 32];

    const int tid  = threadIdx.x;
    const int lane = tid & 63;
    const int wid  = tid >> 6;
    const int l16  = lane & 15;
    const int quad = lane >> 4;
    const int m0   = blockIdx.y * 128;
    const int n0   = blockIdx.x * 64;

    v4f acc[2][4];
    #pragma unroll
    for (int i = 0; i < 2; ++i)
        #pragma unroll
        for (int j = 0; j < 4; ++j) acc[i][j] = (v4f){0.f, 0.f, 0.f, 0.f};

    for (int k0 = 0; k0 < K; k0 += 32) {
        __syncthreads();
        {
            const ushort* ag = A + (size_t)(m0 + wid * 32 + (lane >> 2)) * K + k0 + (lane & 3) * 8;
            async16(ag,                  &As[(wid * 32) * 32]);
            async16(ag + (size_t)16 * K, &As[(wid * 32 + 16) * 32]);
            const ushort* bg = Bt + (size_t)(n0 + wid * 16 + (lane >> 2)) * K + k0 + (lane & 3) * 8;
            async16(bg, &Bs[(wid * 16) * 32]);
        }
        __syncthreads();

        short8 af[2], bf[4];
        #pragma unroll
        for (int i = 0; i < 2; ++i)
            af[i] = *(const short8*)&As[(wid * 32 + i * 16 + l16) * 32 + quad * 8];
        #pragma unroll
        for (int j = 0; j < 4; ++j)
            bf[j] = *(const short8*)&Bs[(j * 16 + l16) * 32 + quad * 8];
        #pragma unroll
        for (int i = 0; i < 2; ++i)
            #pragma unroll
            for (int j = 0; j < 4; ++j)
                acc[i][j] = __builtin_amdgcn_mfma_f32_16x16x32_bf16(af[i], bf[j], acc[i][j], 0, 0, 0);
    }

    if (ROPE && n0 >= 1280) {
        // v tile: store transposed to vT[(b*256 + (col-1280))][t]
        #pragma unroll
        for (int i = 0; i < 2; ++i) {
            const int row = m0 + wid * 32 + i * 16 + quad * 4;   // 4 consecutive t
            const int bb  = row >> 11;
            const int t   = row & (T_ - 1);
            #pragma unroll
            for (int j = 0; j < 4; ++j) {
                const int vc = n0 - 1280 + j * 16 + l16;
                ushort4 o;
                o.x = f2bf(acc[i][j][0]); o.y = f2bf(acc[i][j][1]);
                o.z = f2bf(acc[i][j][2]); o.w = f2bf(acc[i][j][3]);
                *(ushort4*)(vTout + (size_t)(bb * 256 + vc) * T_ + t) = o;
            }
        }
        return;
    }

    if (ROPE) {
        // q gets 0.125 * log2(e) so attention works in exp2 domain
        const float qs = (n0 < 1024) ? 0.18033688f : 1.0f;
        #pragma unroll
        for (int i = 0; i < 2; ++i) {
            #pragma unroll
            for (int r = 0; r < 4; ++r) {
                const int row = m0 + wid * 32 + i * 16 + quad * 4 + r;
                const int t = row & (T_ - 1);
                #pragma unroll
                for (int j = 0; j < 2; ++j) {
                    const int d = j * 16 + l16;
                    float cv = cs[t * 32 + d] * qs, sv = sn[t * 32 + d] * qs;
                    float x1 = acc[i][j][r], x2 = acc[i][j + 2][r];
                    acc[i][j][r]     = x1 * cv - x2 * sv;
                    acc[i][j + 2][r] = x2 * cv + x1 * sv;
                }
            }
        }
    }

    #pragma unroll
    for (int i = 0; i < 2; ++i) {
        #pragma unroll
        for (int r = 0; r < 4; ++r) {
            const int row = m0 + wid * 32 + i * 16 + quad * 4 + r;
            #pragma unroll
            for (int j = 0; j < 4; ++j) {
                const int col = n0 + j * 16 + l16;
                if (BF16OUT)
                    ((ushort*)Cout)[(size_t)row * N + col] = f2bf(acc[i][j][r]);
                else
                    ((float*)Cout)[(size_t)row * N + col] = acc[i][j][r];
            }
        }
    }
}

// ---------------- MFMA flash attention: 128-key chunks, V via LDS ---------
// Grid 512, XCD swizzle (K/V slice L2-resident), paired q-tiles (31-p, p),
// 128-key chunks. V staged via async16 into LDS once per chunk.
// R10 bugs fixed here:
//  (1) V swizzle row index is PER-CALL: rows +0/+4/+8/+12 change (d&15) by
//      4 each call, so each async16 gets its own XOR'd source offset.
//  (2) cross-wave DMA visibility: every wave reads V rows staged by OTHER
//      waves -> per-wave vmcnt is insufficient; raw s_barrier (no compiler
//      vmcnt(0), keeps K-prefetch in flight) after the per-wave V drain.
#define PSTR 136
__global__ __launch_bounds__(256, 2) void attn_mfma(
    const ushort* __restrict__ qkv, const ushort* __restrict__ vT,
    ushort* __restrict__ y)
{
    __shared__ __align__(16) short Ks[2][128 * 64];   // [key][d] 128B rows
    __shared__ __align__(16) short Vs[64 * 128];      // [d][key] 256B rows
    __shared__ __align__(16) short Ps[4][16][PSTR];

    const int tid  = threadIdx.x;
    const int wid  = tid >> 6;
    const int ln   = tid & 63;
    const int l16  = ln & 15;
    const int quad = ln >> 4;

    const int bi   = blockIdx.x;          // 0..511
    const int xcd  = bi & 7;
    const int b    = xcd >> 2;
    const int kvh  = xcd & 3;
    const int jj   = bi >> 3;             // 0..63
    const int h    = kvh * 4 + (jj & 3);
    const int pr   = jj >> 2;             // 0..15

    const ushort* kbase = qkv + (size_t)(b * T_) * QKVN + 1024 + kvh * HD;
    const ushort* vtb   = vT + (size_t)(b * 256 + kvh * HD) * T_;

    // K staging: wave stages rows r0..r0+31 (128B rows, 8 x16B blocks/row)
    const int r0   = wid * 32;
    const int srow = ln >> 3;                     // 0..7
    const int sblk = ((ln & 7) ^ srow) * 8;       // XOR-swizzled source col
    const int sl0  = (quad ^ (l16 & 7)) * 8;      // K frag slot, d-blocks 0..3
    const int sl1  = sl0 ^ 32;                    // d-blocks 4..7
    // V staging: wave stages d-rows vr0..vr0+15 (256B rows, 16 x16B blocks)
    const int vr0  = wid * 16;
    const int vrow = ln >> 4;                     // 0..3
    const int vs4  = ln & 15;                     // LDS slot within row

    #pragma unroll 1
    for (int pass = 0; pass < 2; ++pass) {
        const int tb = pass ? pr : (31 - pr);     // heavy tile first
        const int q0 = tb * 64;
        const int nch = tb / 2 + 1;               // 128-key chunks

        // Q B-fragments (pre-scaled by 0.125*log2e): B[n=l16][k=quad*8+j]
        short8 qf0, qf1;
        {
            const ushort* qrow = qkv + (size_t)(b * T_ + q0 + wid * 16 + l16) * QKVN + h * HD;
            qf0 = *(const short8*)(qrow + quad * 8);
            qf1 = *(const short8*)(qrow + 32 + quad * 8);
        }

        v4f oacc[4];
        #pragma unroll
        for (int t = 0; t < 4; ++t) oacc[t] = (v4f){0.f, 0.f, 0.f, 0.f};
        float m = -1e30f, l = 0.f;

        if (pass) __syncthreads();   // protect Ks/Vs reuse across passes

        // prologue: stage K chunk 0 (128 rows) into buf 0
        {
            const ushort* kg = kbase + (size_t)(r0 + srow) * QKVN + sblk;
            async16(kg,                     &Ks[0][(r0     ) * 64]);
            async16(kg + (size_t) 8 * QKVN, &Ks[0][(r0 +  8) * 64]);
            async16(kg + (size_t)16 * QKVN, &Ks[0][(r0 + 16) * 64]);
            async16(kg + (size_t)24 * QKVN, &Ks[0][(r0 + 24) * 64]);
        }

        for (int c = 0; c < nch; ++c) {
            const int key0 = c * 128;
            __syncthreads();   // per-wave vmcnt(0): K chunk-c DMA drained; V area free

            // stage V chunk c into LDS (single buffer). Swizzle: slot vs4 of
            // d-row d holds global key-block vs4 ^ (d&15); (d&15) = vrow+it*4
            // differs per call -> per-call source offset (R10 bug #1 fix).
            {
                const ushort* vg = vtb + (size_t)(vr0 + vrow) * T_ + key0;
                async16(vg                  + (vs4 ^ (vrow     )) * 8, &Vs[(vr0     ) * 128]);
                async16(vg + (size_t) 4 * T_ + (vs4 ^ (vrow +  4)) * 8, &Vs[(vr0 +  4) * 128]);
                async16(vg + (size_t) 8 * T_ + (vs4 ^ (vrow +  8)) * 8, &Vs[(vr0 +  8) * 128]);
                async16(vg + (size_t)12 * T_ + (vs4 ^ (vrow + 12)) * 8, &Vs[(vr0 + 12) * 128]);
            }
            // prefetch K chunk c+1
            const bool kpref = (c + 1 < nch);
            if (kpref) {
                const int nb = (c + 1) & 1;
                const ushort* kg = kbase + (size_t)(key0 + 128 + r0 + srow) * QKVN + sblk;
                async16(kg,                     &Ks[nb][(r0     ) * 64]);
                async16(kg + (size_t) 8 * QKVN, &Ks[nb][(r0 +  8) * 64]);
                async16(kg + (size_t)16 * QKVN, &Ks[nb][(r0 + 16) * 64]);
                async16(kg + (size_t)24 * QKVN, &Ks[nb][(r0 + 24) * 64]);
            }
            const short* Kb = Ks[c & 1];

            // ---- S^T = K @ Q^T (row=key, col=query), 8 key-tiles ----
            v4f st[8];
            #pragma unroll
            for (int t = 0; t < 8; ++t) {
                short8 k0f = *(const short8*)&Kb[(t * 16 + l16) * 64 + sl0];
                short8 k1f = *(const short8*)&Kb[(t * 16 + l16) * 64 + sl1];
                v4f s = (v4f){0.f, 0.f, 0.f, 0.f};
                s = __builtin_amdgcn_mfma_f32_16x16x32_bf16(k0f, qf0, s, 0, 0, 0);
                s = __builtin_amdgcn_mfma_f32_16x16x32_bf16(k1f, qf1, s, 0, 0, 0);
                st[t] = s;
            }

            // causal mask: only the chunk containing the diagonal
            if (c == nch - 1) {
                const int qg = wid * 16 + l16 + q0;
                #pragma unroll
                for (int t = 0; t < 8; ++t)
                    #pragma unroll
                    for (int r = 0; r < 4; ++r)
                        if (key0 + t * 16 + quad * 4 + r > qg) st[t][r] = -1e30f;
            }

            // ---- online softmax (exp2 domain), per-lane query scalar ----
            float mx = st[0][0];
            #pragma unroll
            for (int t = 0; t < 8; ++t)
                #pragma unroll
                for (int r = 0; r < 4; ++r) mx = fmaxf(mx, st[t][r]);
            mx = fmaxf(mx, __shfl_xor(mx, 16, 64));
            mx = fmaxf(mx, __shfl_xor(mx, 32, 64));
            float mnew  = fmaxf(m, mx);
            float alpha = ex2(m - mnew);
            m = mnew;
            float p[8][4], sum = 0.f;
            #pragma unroll
            for (int t = 0; t < 8; ++t)
                #pragma unroll
                for (int r = 0; r < 4; ++r) {
                    p[t][r] = ex2(st[t][r] - mnew);
                    sum += p[t][r];
                }
            sum += __shfl_xor(sum, 16, 64);
            sum += __shfl_xor(sum, 32, 64);
            l = l * alpha + sum;

            // write P^T rows: Ps[query=l16][key], packed pairs -> b64
            #pragma unroll
            for (int t = 0; t < 8; ++t) {
                uint2 w;
                w.x = pk_bf16(p[t][0], p[t][1]);
                w.y = pk_bf16(p[t][2], p[t][3]);
                *(uint2*)&Ps[wid][l16][t * 16 + quad * 4] = w;
            }
            #pragma unroll
            for (int t = 0; t < 4; ++t)
                #pragma unroll
                for (int r = 0; r < 4; ++r) oacc[t][r] *= alpha;

            // drain this wave's P ds_writes
            asm volatile("s_waitcnt lgkmcnt(0)" ::: "memory");
            short8 pa[4];
            #pragma unroll
            for (int seg = 0; seg < 4; ++seg)
                pa[seg] = *(const short8*)&Ps[wid][l16][seg * 32 + quad * 8];

            // V visibility (R10 bug #2 fix): drain own V DMAs (vmcnt(4)
            // leaves the 4 K-prefetch in flight; vmcnt(0) on last chunk),
            // then RAW s_barrier so ALL waves' V rows are visible. Raw
            // barrier avoids __syncthreads' compiler-forced vmcnt(0) which
            // would kill the K-prefetch overlap. Uniform branch: no hazard.
            if (kpref) asm volatile("s_waitcnt vmcnt(4)\n\ts_barrier" ::: "memory");
            else       asm volatile("s_waitcnt vmcnt(0)\n\ts_barrier" ::: "memory");

            // ---- O^T += V^T @ P^T : V frags from LDS (swizzled rows) ----
            #pragma unroll
            for (int t = 0; t < 4; ++t) {
                const int dr = t * 16 + l16;          // V d-row
                #pragma unroll
                for (int seg = 0; seg < 4; ++seg) {
                    const int slot = ((seg * 4 + quad) ^ dr) & 15;
                    short8 vv = *(const short8*)&Vs[dr * 128 + slot * 8];
                    oacc[t] = __builtin_amdgcn_mfma_f32_16x16x32_bf16(vv, pa[seg], oacc[t], 0, 0, 0);
                }
            }
        }

        // epilogue: y[query][h*64+d] = O^T / l
        const float inv = 1.0f / l;
        ushort* yrow = y + (size_t)(b * T_ + q0 + wid * 16 + l16) * (NH * HD) + h * HD;
        #pragma unroll
        for (int t = 0; t < 4; ++t) {
            ushort4 o;
            o.x = f2bf(oacc[t][0] * inv); o.y = f2bf(oacc[t][1] * inv);
            o.z = f2bf(oacc[t][2] * inv); o.w = f2bf(oacc[t][3] * inv);
            *(ushort4*)(yrow + t * 16 + quad * 4) = o;
        }
    }
}

// ---------------- launcher ----------------
extern "C" void kernel_launch(void* const* d_in, const int* in_sizes, int n_in,
                              void* d_out, int out_size, void* d_ws, size_t ws_size,
                              hipStream_t stream)
{
    const float* x    = (const float*)d_in[0];
    const float* cosT = (const float*)d_in[1];
    const float* sinT = (const float*)d_in[2];
    const float* Wq   = (const float*)d_in[3];
    const float* Wk   = (const float*)d_in[4];
    const float* Wv   = (const float*)d_in[5];
    const float* Wo   = (const float*)d_in[6];
    float* out = (float*)d_out;

    const int M = B_ * T_;  // 4096
    ushort* xb     = (ushort*)d_ws;                       // 4096*1024
    ushort* qkv    = xb  + (size_t)M * C_;                // 4096*1536
    ushort* yb     = qkv + (size_t)M * QKVN;              // 4096*1024
    ushort* WqkvT  = yb  + (size_t)M * C_;                // 1536*1024
    ushort* WoT    = WqkvT + (size_t)QKVN * C_;           // 1024*1024
    ushort* vTbuf  = WoT + (size_t)C_ * C_;               // 2*256*2048

    dim3 blk(256);
    // converts + weight transposes, one launch
    prep<<<640 + (M * C_) / 1024, blk, 0, stream>>>(x, Wq, Wk, Wv, Wo, xb, WqkvT, WoT);
    // fused QKV projection: rope(+exp2 scale) epilogue, v written straight to vT
    gemm_bf16bt<true, true><<<dim3(QKVN / 64, M / 128), blk, 0, stream>>>(
        xb, WqkvT, qkv, vTbuf, cosT, sinT, M, QKVN, C_);
    // attention (XCD-swizzled, paired tiles, 128-key chunks, V via LDS)
    attn_mfma<<<512, blk, 0, stream>>>(qkv, vTbuf, yb);
    // output projection (fp32 out)
    gemm_bf16bt<false, false><<<dim3(C_ / 64, M / 128), blk, 0, stream>>>(
        yb, WoT, out, nullptr, nullptr, nullptr, M, C_, C_);
}

// Round 12
// 169.944 us; speedup vs baseline: 1.2693x; 1.0077x over previous
//
#include <hip/hip_runtime.h>
#include <hip/hip_bf16.h>
#include <math.h>

#define NH   16
#define NKV  4
#define HD   64
#define B_   2
#define T_   2048
#define C_   1024
#define QKVN 1536   // fused q(1024) | k(256) | v(256)

typedef __attribute__((ext_vector_type(8))) short short8;
typedef __attribute__((ext_vector_type(4))) float v4f;

__device__ inline ushort f2bf(float f) {
    union { float f; uint32_t u; } v; v.f = f;
    uint32_t r = v.u + 0x7fffu + ((v.u >> 16) & 1u);
    return (ushort)(r >> 16);
}

// pack two f32 -> one dword of bf16
__device__ inline uint pk_bf16(float a, float b) {
#if __has_builtin(__builtin_amdgcn_cvt_pk_bf16_f32)
    auto v = __builtin_amdgcn_cvt_pk_bf16_f32(a, b);
    union { decltype(v) v2; uint u; } cv; cv.v2 = v; return cv.u;
#else
    return (uint)f2bf(a) | ((uint)f2bf(b) << 16);
#endif
}

__device__ inline float ex2(float x) {
#if __has_builtin(__builtin_amdgcn_exp2f)
    return __builtin_amdgcn_exp2f(x);
#else
    return exp2f(x);
#endif
}

// async global->LDS, 16B per lane; LDS dest wave-uniform base + lane*16
__device__ inline void async16(const void* g, void* l) {
    __builtin_amdgcn_global_load_lds(
        (const __attribute__((address_space(1))) unsigned int*)g,
        (__attribute__((address_space(3))) unsigned int*)l, 16, 0, 0);
}

// ---------------- prep: x f32->bf16 convert + 4 weight transposes ----------
__global__ __launch_bounds__(256) void prep(
    const float* __restrict__ x,
    const float* __restrict__ Wq, const float* __restrict__ Wk,
    const float* __restrict__ Wv, const float* __restrict__ Wo,
    ushort* __restrict__ xb, ushort* __restrict__ WqkvT, ushort* __restrict__ WoT)
{
    const int bx = blockIdx.x;
    const int tid = threadIdx.x;
    if (bx < 640) {
        __shared__ float tile[64][65];
        const int cb = bx >> 4;
        const int kb = bx & 15;
        const float* src; ushort* dst; int N, nb;
        if (cb < 16)      { src = Wq; dst = WqkvT;                     N = 1024; nb = cb; }
        else if (cb < 20) { src = Wk; dst = WqkvT + (size_t)1024 * C_; N = 256;  nb = cb - 16; }
        else if (cb < 24) { src = Wv; dst = WqkvT + (size_t)1280 * C_; N = 256;  nb = cb - 20; }
        else              { src = Wo; dst = WoT;                       N = 1024; nb = cb - 24; }
        const int k0 = kb * 64, n0 = nb * 64;
        #pragma unroll
        for (int it = 0; it < 4; ++it) {
            int r = (tid >> 4) + it * 16;
            int c = (tid & 15) * 4;
            float4 v = *(const float4*)(src + (size_t)(k0 + r) * N + n0 + c);
            tile[r][c] = v.x; tile[r][c + 1] = v.y; tile[r][c + 2] = v.z; tile[r][c + 3] = v.w;
        }
        __syncthreads();
        #pragma unroll
        for (int it = 0; it < 4; ++it) {
            int r = (tid >> 4) + it * 16;
            int c = (tid & 15) * 4;
            ushort4 o;
            o.x = f2bf(tile[c + 0][r]); o.y = f2bf(tile[c + 1][r]);
            o.z = f2bf(tile[c + 2][r]); o.w = f2bf(tile[c + 3][r]);
            *(ushort4*)(dst + (size_t)(n0 + r) * C_ + k0 + c) = o;
        }
    } else {
        int i = ((bx - 640) * 256 + tid) * 4;   // covers 4096*1024 exactly
        float4 v = *(const float4*)(x + i);
        ushort4 o; o.x = f2bf(v.x); o.y = f2bf(v.y); o.z = f2bf(v.z); o.w = f2bf(v.w);
        *(ushort4*)(xb + i) = o;
    }
}

// ---------------- bf16 MFMA GEMM: C[M,N] = A[M,K] @ Bt[N,K]^T --------------
// 128(M)x64(N) tile, BK=32, 4 waves stacked along M (wave: 32m x 64n).
// R12: K-loop software-pipelined like the attention kernel — double-buffered
// LDS, ONE barrier per iter (vmcnt(0) drains own buf-i DMA; raw s_barrier
// publishes it), prefetch of buf i+1 issued after the barrier so its DMA
// latency overlaps the whole compute of iter i. (The old 2-barrier loop
// exposed the full global latency every one of the 32 iterations.)
// ROPE path (QKV gemm): n0<1024 -> rope + 0.125*log2e scale (exp2 softmax);
// 1024..1280 -> rope only (k); n0>=1280 -> v stored transposed into vT.
template <bool BF16OUT, bool ROPE>
__global__ __launch_bounds__(256) void gemm_bf16bt(
    const ushort* __restrict__ A, const ushort* __restrict__ Bt,
    void* __restrict__ Cout, ushort* __restrict__ vTout,
    const float* __restrict__ cs, const float* __restrict__ sn,
    int M, int N, int K)
{
    __shared__ __align__(16) short As[2][128 * 32];
    __shared__ __align__(16) short Bs[2][64 * 32];

    const int tid  = threadIdx.x;
    const int lane = tid & 63;
    const int wid  = tid >> 6;
    const int l16  = lane & 15;
    const int quad = lane >> 4;
    const int m0   = blockIdx.y * 128;
    const int n0   = blockIdx.x * 64;

    const ushort* agb = A  + (size_t)(m0 + wid * 32 + (lane >> 2)) * K + (lane & 3) * 8;
    const ushort* bgb = Bt + (size_t)(n0 + wid * 16 + (lane >> 2)) * K + (lane & 3) * 8;

    v4f acc[2][4];
    #pragma unroll
    for (int i = 0; i < 2; ++i)
        #pragma unroll
        for (int j = 0; j < 4; ++j) acc[i][j] = (v4f){0.f, 0.f, 0.f, 0.f};

    // prologue: stage iter 0 into buf 0
    async16(agb,                  &As[0][(wid * 32) * 32]);
    async16(agb + (size_t)16 * K, &As[0][(wid * 32 + 16) * 32]);
    async16(bgb,                  &Bs[0][(wid * 16) * 32]);

    const int nIter = K >> 5;
    for (int it = 0; it < nIter; ++it) {
        // drain own buf-it DMA (only thing in flight), publish to block.
        // raw barrier: no compiler-forced full drain beyond what we ask.
        asm volatile("s_waitcnt vmcnt(0)\n\ts_barrier" ::: "memory");

        // prefetch iter it+1 into the other buffer; in flight across compute.
        // Safe: barrier above ordered all waves past their iter it-1 compute,
        // so buf (it+1)&1 (= buf it-1's region) is no longer being read.
        if (it + 1 < nIter) {
            const int nb = (it + 1) & 1;
            const int k0 = (it + 1) << 5;
            async16(agb + k0,                  &As[nb][(wid * 32) * 32]);
            async16(agb + k0 + (size_t)16 * K, &As[nb][(wid * 32 + 16) * 32]);
            async16(bgb + k0,                  &Bs[nb][(wid * 16) * 32]);
        }

        const short* Ab = As[it & 1];
        const short* Bb = Bs[it & 1];
        short8 af[2], bf[4];
        #pragma unroll
        for (int i = 0; i < 2; ++i)
            af[i] = *(const short8*)&Ab[(wid * 32 + i * 16 + l16) * 32 + quad * 8];
        #pragma unroll
        for (int j = 0; j < 4; ++j)
            bf[j] = *(const short8*)&Bb[(j * 16 + l16) * 32 + quad * 8];
        #pragma unroll
        for (int i = 0; i < 2; ++i)
            #pragma unroll
            for (int j = 0; j < 4; ++j)
                acc[i][j] = __builtin_amdgcn_mfma_f32_16x16x32_bf16(af[i], bf[j], acc[i][j], 0, 0, 0);
    }

    if (ROPE && n0 >= 1280) {
        // v tile: store transposed to vT[(b*256 + (col-1280))][t]
        #pragma unroll
        for (int i = 0; i < 2; ++i) {
            const int row = m0 + wid * 32 + i * 16 + quad * 4;   // 4 consecutive t
            const int bb  = row >> 11;
            const int t   = row & (T_ - 1);
            #pragma unroll
            for (int j = 0; j < 4; ++j) {
                const int vc = n0 - 1280 + j * 16 + l16;
                ushort4 o;
                o.x = f2bf(acc[i][j][0]); o.y = f2bf(acc[i][j][1]);
                o.z = f2bf(acc[i][j][2]); o.w = f2bf(acc[i][j][3]);
                *(ushort4*)(vTout + (size_t)(bb * 256 + vc) * T_ + t) = o;
            }
        }
        return;
    }

    if (ROPE) {
        // q gets 0.125 * log2(e) so attention works in exp2 domain
        const float qs = (n0 < 1024) ? 0.18033688f : 1.0f;
        #pragma unroll
        for (int i = 0; i < 2; ++i) {
            #pragma unroll
            for (int r = 0; r < 4; ++r) {
                const int row = m0 + wid * 32 + i * 16 + quad * 4 + r;
                const int t = row & (T_ - 1);
                #pragma unroll
                for (int j = 0; j < 2; ++j) {
                    const int d = j * 16 + l16;
                    float cv = cs[t * 32 + d] * qs, sv = sn[t * 32 + d] * qs;
                    float x1 = acc[i][j][r], x2 = acc[i][j + 2][r];
                    acc[i][j][r]     = x1 * cv - x2 * sv;
                    acc[i][j + 2][r] = x2 * cv + x1 * sv;
                }
            }
        }
    }

    #pragma unroll
    for (int i = 0; i < 2; ++i) {
        #pragma unroll
        for (int r = 0; r < 4; ++r) {
            const int row = m0 + wid * 32 + i * 16 + quad * 4 + r;
            #pragma unroll
            for (int j = 0; j < 4; ++j) {
                const int col = n0 + j * 16 + l16;
                if (BF16OUT)
                    ((ushort*)Cout)[(size_t)row * N + col] = f2bf(acc[i][j][r]);
                else
                    ((float*)Cout)[(size_t)row * N + col] = acc[i][j][r];
            }
        }
    }
}

// ---------------- MFMA flash attention: 128-key chunks, V via LDS ---------
// (R11 verbatim — passing at 46.5 µs.)
// Grid 512, XCD swizzle (K/V slice L2-resident), paired q-tiles (31-p, p),
// 128-key chunks, V staged via async16 with per-call swizzle, raw-barrier
// V visibility.
#define PSTR 136
__global__ __launch_bounds__(256, 2) void attn_mfma(
    const ushort* __restrict__ qkv, const ushort* __restrict__ vT,
    ushort* __restrict__ y)
{
    __shared__ __align__(16) short Ks[2][128 * 64];   // [key][d] 128B rows
    __shared__ __align__(16) short Vs[64 * 128];      // [d][key] 256B rows
    __shared__ __align__(16) short Ps[4][16][PSTR];

    const int tid  = threadIdx.x;
    const int wid  = tid >> 6;
    const int ln   = tid & 63;
    const int l16  = ln & 15;
    const int quad = ln >> 4;

    const int bi   = blockIdx.x;          // 0..511
    const int xcd  = bi & 7;
    const int b    = xcd >> 2;
    const int kvh  = xcd & 3;
    const int jj   = bi >> 3;             // 0..63
    const int h    = kvh * 4 + (jj & 3);
    const int pr   = jj >> 2;             // 0..15

    const ushort* kbase = qkv + (size_t)(b * T_) * QKVN + 1024 + kvh * HD;
    const ushort* vtb   = vT + (size_t)(b * 256 + kvh * HD) * T_;

    // K staging: wave stages rows r0..r0+31 (128B rows, 8 x16B blocks/row)
    const int r0   = wid * 32;
    const int srow = ln >> 3;                     // 0..7
    const int sblk = ((ln & 7) ^ srow) * 8;       // XOR-swizzled source col
    const int sl0  = (quad ^ (l16 & 7)) * 8;      // K frag slot, d-blocks 0..3
    const int sl1  = sl0 ^ 32;                    // d-blocks 4..7
    // V staging: wave stages d-rows vr0..vr0+15 (256B rows, 16 x16B blocks)
    const int vr0  = wid * 16;
    const int vrow = ln >> 4;                     // 0..3
    const int vs4  = ln & 15;                     // LDS slot within row

    #pragma unroll 1
    for (int pass = 0; pass < 2; ++pass) {
        const int tb = pass ? pr : (31 - pr);     // heavy tile first
        const int q0 = tb * 64;
        const int nch = tb / 2 + 1;               // 128-key chunks

        // Q B-fragments (pre-scaled by 0.125*log2e): B[n=l16][k=quad*8+j]
        short8 qf0, qf1;
        {
            const ushort* qrow = qkv + (size_t)(b * T_ + q0 + wid * 16 + l16) * QKVN + h * HD;
            qf0 = *(const short8*)(qrow + quad * 8);
            qf1 = *(const short8*)(qrow + 32 + quad * 8);
        }

        v4f oacc[4];
        #pragma unroll
        for (int t = 0; t < 4; ++t) oacc[t] = (v4f){0.f, 0.f, 0.f, 0.f};
        float m = -1e30f, l = 0.f;

        if (pass) __syncthreads();   // protect Ks/Vs reuse across passes

        // prologue: stage K chunk 0 (128 rows) into buf 0
        {
            const ushort* kg = kbase + (size_t)(r0 + srow) * QKVN + sblk;
            async16(kg,                     &Ks[0][(r0     ) * 64]);
            async16(kg + (size_t) 8 * QKVN, &Ks[0][(r0 +  8) * 64]);
            async16(kg + (size_t)16 * QKVN, &Ks[0][(r0 + 16) * 64]);
            async16(kg + (size_t)24 * QKVN, &Ks[0][(r0 + 24) * 64]);
        }

        for (int c = 0; c < nch; ++c) {
            const int key0 = c * 128;
            __syncthreads();   // per-wave vmcnt(0): K chunk-c DMA drained; V area free

            // stage V chunk c into LDS (single buffer). Swizzle: slot vs4 of
            // d-row d holds global key-block vs4 ^ (d&15); per-call offset.
            {
                const ushort* vg = vtb + (size_t)(vr0 + vrow) * T_ + key0;
                async16(vg                   + (vs4 ^ (vrow     )) * 8, &Vs[(vr0     ) * 128]);
                async16(vg + (size_t) 4 * T_ + (vs4 ^ (vrow +  4)) * 8, &Vs[(vr0 +  4) * 128]);
                async16(vg + (size_t) 8 * T_ + (vs4 ^ (vrow +  8)) * 8, &Vs[(vr0 +  8) * 128]);
                async16(vg + (size_t)12 * T_ + (vs4 ^ (vrow + 12)) * 8, &Vs[(vr0 + 12) * 128]);
            }
            // prefetch K chunk c+1
            const bool kpref = (c + 1 < nch);
            if (kpref) {
                const int nb = (c + 1) & 1;
                const ushort* kg = kbase + (size_t)(key0 + 128 + r0 + srow) * QKVN + sblk;
                async16(kg,                     &Ks[nb][(r0     ) * 64]);
                async16(kg + (size_t) 8 * QKVN, &Ks[nb][(r0 +  8) * 64]);
                async16(kg + (size_t)16 * QKVN, &Ks[nb][(r0 + 16) * 64]);
                async16(kg + (size_t)24 * QKVN, &Ks[nb][(r0 + 24) * 64]);
            }
            const short* Kb = Ks[c & 1];

            // ---- S^T = K @ Q^T (row=key, col=query), 8 key-tiles ----
            v4f st[8];
            #pragma unroll
            for (int t = 0; t < 8; ++t) {
                short8 k0f = *(const short8*)&Kb[(t * 16 + l16) * 64 + sl0];
                short8 k1f = *(const short8*)&Kb[(t * 16 + l16) * 64 + sl1];
                v4f s = (v4f){0.f, 0.f, 0.f, 0.f};
                s = __builtin_amdgcn_mfma_f32_16x16x32_bf16(k0f, qf0, s, 0, 0, 0);
                s = __builtin_amdgcn_mfma_f32_16x16x32_bf16(k1f, qf1, s, 0, 0, 0);
                st[t] = s;
            }

            // causal mask: only the chunk containing the diagonal
            if (c == nch - 1) {
                const int qg = wid * 16 + l16 + q0;
                #pragma unroll
                for (int t = 0; t < 8; ++t)
                    #pragma unroll
                    for (int r = 0; r < 4; ++r)
                        if (key0 + t * 16 + quad * 4 + r > qg) st[t][r] = -1e30f;
            }

            // ---- online softmax (exp2 domain), per-lane query scalar ----
            float mx = st[0][0];
            #pragma unroll
            for (int t = 0; t < 8; ++t)
                #pragma unroll
                for (int r = 0; r < 4; ++r) mx = fmaxf(mx, st[t][r]);
            mx = fmaxf(mx, __shfl_xor(mx, 16, 64));
            mx = fmaxf(mx, __shfl_xor(mx, 32, 64));
            float mnew  = fmaxf(m, mx);
            float alpha = ex2(m - mnew);
            m = mnew;
            float p[8][4], sum = 0.f;
            #pragma unroll
            for (int t = 0; t < 8; ++t)
                #pragma unroll
                for (int r = 0; r < 4; ++r) {
                    p[t][r] = ex2(st[t][r] - mnew);
                    sum += p[t][r];
                }
            sum += __shfl_xor(sum, 16, 64);
            sum += __shfl_xor(sum, 32, 64);
            l = l * alpha + sum;

            // write P^T rows: Ps[query=l16][key], packed pairs -> b64
            #pragma unroll
            for (int t = 0; t < 8; ++t) {
                uint2 w;
                w.x = pk_bf16(p[t][0], p[t][1]);
                w.y = pk_bf16(p[t][2], p[t][3]);
                *(uint2*)&Ps[wid][l16][t * 16 + quad * 4] = w;
            }
            #pragma unroll
            for (int t = 0; t < 4; ++t)
                #pragma unroll
                for (int r = 0; r < 4; ++r) oacc[t][r] *= alpha;

            // drain this wave's P ds_writes
            asm volatile("s_waitcnt lgkmcnt(0)" ::: "memory");
            short8 pa[4];
            #pragma unroll
            for (int seg = 0; seg < 4; ++seg)
                pa[seg] = *(const short8*)&Ps[wid][l16][seg * 32 + quad * 8];

            // V visibility: drain own V DMAs (vmcnt(4) keeps K-prefetch in
            // flight; vmcnt(0) on last chunk), then RAW s_barrier so ALL
            // waves' V rows are visible.
            if (kpref) asm volatile("s_waitcnt vmcnt(4)\n\ts_barrier" ::: "memory");
            else       asm volatile("s_waitcnt vmcnt(0)\n\ts_barrier" ::: "memory");

            // ---- O^T += V^T @ P^T : V frags from LDS (swizzled rows) ----
            #pragma unroll
            for (int t = 0; t < 4; ++t) {
                const int dr = t * 16 + l16;          // V d-row
                #pragma unroll
                for (int seg = 0; seg < 4; ++seg) {
                    const int slot = ((seg * 4 + quad) ^ dr) & 15;
                    short8 vv = *(const short8*)&Vs[dr * 128 + slot * 8];
                    oacc[t] = __builtin_amdgcn_mfma_f32_16x16x32_bf16(vv, pa[seg], oacc[t], 0, 0, 0);
                }
            }
        }

        // epilogue: y[query][h*64+d] = O^T / l
        const float inv = 1.0f / l;
        ushort* yrow = y + (size_t)(b * T_ + q0 + wid * 16 + l16) * (NH * HD) + h * HD;
        #pragma unroll
        for (int t = 0; t < 4; ++t) {
            ushort4 o;
            o.x = f2bf(oacc[t][0] * inv); o.y = f2bf(oacc[t][1] * inv);
            o.z = f2bf(oacc[t][2] * inv); o.w = f2bf(oacc[t][3] * inv);
            *(ushort4*)(yrow + t * 16 + quad * 4) = o;
        }
    }
}

// ---------------- launcher ----------------
extern "C" void kernel_launch(void* const* d_in, const int* in_sizes, int n_in,
                              void* d_out, int out_size, void* d_ws, size_t ws_size,
                              hipStream_t stream)
{
    const float* x    = (const float*)d_in[0];
    const float* cosT = (const float*)d_in[1];
    const float* sinT = (const float*)d_in[2];
    const float* Wq   = (const float*)d_in[3];
    const float* Wk   = (const float*)d_in[4];
    const float* Wv   = (const float*)d_in[5];
    const float* Wo   = (const float*)d_in[6];
    float* out = (float*)d_out;

    const int M = B_ * T_;  // 4096
    ushort* xb     = (ushort*)d_ws;                       // 4096*1024
    ushort* qkv    = xb  + (size_t)M * C_;                // 4096*1536
    ushort* yb     = qkv + (size_t)M * QKVN;              // 4096*1024
    ushort* WqkvT  = yb  + (size_t)M * C_;                // 1536*1024
    ushort* WoT    = WqkvT + (size_t)QKVN * C_;           // 1024*1024
    ushort* vTbuf  = WoT + (size_t)C_ * C_;               // 2*256*2048

    dim3 blk(256);
    // converts + weight transposes, one launch
    prep<<<640 + (M * C_) / 1024, blk, 0, stream>>>(x, Wq, Wk, Wv, Wo, xb, WqkvT, WoT);
    // fused QKV projection: rope(+exp2 scale) epilogue, v written straight to vT
    gemm_bf16bt<true, true><<<dim3(QKVN / 64, M / 128), blk, 0, stream>>>(
        xb, WqkvT, qkv, vTbuf, cosT, sinT, M, QKVN, C_);
    // attention (XCD-swizzled, paired tiles, 128-key chunks, V via LDS)
    attn_mfma<<<512, blk, 0, stream>>>(qkv, vTbuf, yb);
    // output projection (fp32 out)
    gemm_bf16bt<false, false><<<dim3(C_ / 64, M / 128), blk, 0, stream>>>(
        yb, WoT, out, nullptr, nullptr, nullptr, M, C_, C_);
}